// Round 13
// baseline (97.882 us; speedup 1.0000x reference)
//
#include <hip/hip_runtime.h>

// (B,H,W,C) = (16,512,512,3) float32. 4 warp ops.
// out concat order: 0:(frame1,f01) 1:(frame0,f10) 2:(frame0,ft0) 3:(frame1,ft1)
#define HH 512
#define WW 512
#define NPIX (16 * HH * WW)
#define IMG_DW (HH * WW * 3)     // dwords per image
#define ROWD_G (WW * 3)          // global image row stride in dwords

#define TSX   32                 // output tile width
#define TSY   16                 // output tile height
#define APRX  12                 // x apron
#define APRY  12                 // y apron
#define LWX   (TSX + 2 * APRX)   // 56: staged region width (px)
#define LWY   (TSY + 2 * APRY)   // 40: staged region height (rows)
#define LSTR  (LWX * 3)          // 168: row stride (16B chunk-aligned: 168%4==0)
#define LDSDW (LWY * LSTR)       // 6720 dwords = 26,880 B -> 6 blocks/CU ceiling
#define NCHUNK (LDSDW / 4)       // 1680 16B chunks = 6*256 + 144

typedef float fv4 __attribute__((ext_vector_type(4)));
typedef float fv2 __attribute__((ext_vector_type(2)));
typedef fv4 fv4u __attribute__((aligned(4)));
typedef fv2 fv2u __attribute__((aligned(4)));

// Phase-1 math: query -> clamped integer corner + fractions + in-apron flag.
struct SampCoord { int yl, xl; float ay, ax; bool ok; };

__device__ __forceinline__ SampCoord scoord(float qy, float qx, int AX0, int AY0)
{
    SampCoord sc;
    float fy = floorf(qy); fy = fminf(fmaxf(fy, 0.0f), (float)(HH - 2));
    float fx = floorf(qx); fx = fminf(fmaxf(fx, 0.0f), (float)(WW - 2));
    sc.ay = fminf(fmaxf(qy - fy, 0.0f), 1.0f);
    sc.ax = fminf(fmaxf(qx - fx, 0.0f), 1.0f);
    const int y0 = (int)fy, x0 = (int)fx;
    sc.yl = y0 - AY0; sc.xl = x0 - AX0;
    sc.ok = (unsigned)sc.yl < (unsigned)(LWY - 1) && (unsigned)sc.xl < (unsigned)(LWX - 1);
    return sc;
}

// 12 raw corner values from LDS: issues 6 ds_read2_b32 back-to-back.
__device__ __forceinline__ void load12_lds(const float* __restrict__ s,
                                           const SampCoord& sc, float* __restrict__ v)
{
    const float* t  = s + sc.yl * LSTR + 3 * sc.xl;
#pragma unroll
    for (int c = 0; c < 3; ++c) {
        v[c]     = t[c];            // offsets c / c+3 -> one ds_read2_b32
        v[c + 3] = t[c + 3];
        v[c + 6] = t[LSTR + c];
        v[c + 9] = t[LSTR + c + 3];
    }
}

// 12 raw corner values from global (rare fallback; clamped exact-math path).
__device__ __forceinline__ void load12_glb(const float* __restrict__ imgb,
                                           const SampCoord& sc, int AX0, int AY0,
                                           float* __restrict__ v)
{
    const int y0 = sc.yl + AY0, x0 = sc.xl + AX0;
    const float* t  = imgb + ((size_t)y0 * WW + x0) * 3;
    const float* bo = t + WW * 3;
    const fv4u t4 = *(const fv4u*)t;  const fv2u t2 = *(const fv2u*)(t + 4);
    const fv4u b4 = *(const fv4u*)bo; const fv2u b2 = *(const fv2u*)(bo + 4);
    v[0] = t4.x; v[1] = t4.y; v[2] = t4.z; v[3] = t4.w; v[4] = t2.x; v[5] = t2.y;
    v[6] = b4.x; v[7] = b4.y; v[8] = b4.z; v[9] = b4.w; v[10] = b2.x; v[11] = b2.y;
}

__device__ __forceinline__ void lerp3(const SampCoord& sc, const float* __restrict__ v,
                                      float* __restrict__ r)
{
#pragma unroll
    for (int c = 0; c < 3; ++c) {
        const float top = v[c]     + sc.ax * (v[c + 3] - v[c]);
        const float bot = v[c + 6] + sc.ax * (v[c + 9] - v[c + 6]);
        r[c] = top + sc.ay * (bot - top);
    }
}

__global__ __launch_bounds__(256) void warp_batch_kernel(
    const float* __restrict__ frame0, const float* __restrict__ frame1,
    const float* __restrict__ f01, const float* __restrict__ f10,
    const float* __restrict__ ft0, const float* __restrict__ ft1,
    float* __restrict__ out)
{
    __shared__ float lds[LDSDW];   // 26,880 B

    // 16384 blocks; bijective XCD chunking: XCD k gets 2048 contiguous units
    // = 4 whole (fg,b) images; apron re-reads stay L2-resident.
    const unsigned bid = blockIdx.x;
    const unsigned v   = (bid & 7u) * 2048u + (bid >> 3);

    const unsigned tile  = v & 511u;   // 16 x 32 tiles per image
    const unsigned img_b = v >> 9;     // 0..31
    const int b  = (int)(img_b & 15u);
    const int fg = (int)(img_b >> 4);  // 0: frame0 ops{1,2}, 1: frame1 ops{0,3}

    const int tx = (int)(tile & 15u);
    const int ty = (int)(tile >> 4);
    const int X0 = tx * TSX, Y0 = ty * TSY;
    const int AX0 = X0 - APRX, AY0 = Y0 - APRY;

    const float* img   = fg ? frame1 : frame0;
    const float* flowA = fg ? f01 : f10;
    const float* flowB = fg ? ft1 : ft0;
    const size_t opA   = fg ? 0 : 1;
    const size_t opB   = fg ? 3 : 2;

    const float* imgb = img + (size_t)b * IMG_DW;

    const int tid = (int)threadIdx.x;
    const int lx = (tid & 15) * 2;     // 16 threads x 2 px cover 32 px row
    const int ly = tid >> 4;           // 16 rows
    const int x = X0 + lx, y = Y0 + ly;
    const size_t pixIn = ((size_t)b * HH + y) * WW + x;

    // Flow loads (2 px -> one 16B load per op); consumed after the barrier.
    const fv4 a = __builtin_nontemporal_load((const fv4*)(flowA + pixIn * 2));
    const fv4 c = __builtin_nontemporal_load((const fv4*)(flowB + pixIn * 2));

    // ---- Stage apron region HBM -> LDS via global_load_lds (async, 0 VGPR).
    {
        const unsigned wid = __builtin_amdgcn_readfirstlane((unsigned)tid >> 6);
        int D   = tid * 4;
        int row = D / LSTR;
        int rd  = D - row * LSTR;
#pragma unroll
        for (int it = 0; it < 7; ++it) {
            if (it < 6 || tid < (NCHUNK - 6 * 256)) {   // 144 tail chunks
                const int gy = min(max(AY0 + row, 0), HH - 1);
                int idx = gy * ROWD_G + AX0 * 3 + rd;
                idx = min(max(idx, 0), IMG_DW - 4);     // fault-safety only
                const float* src = imgb + idx;
                float* dst = (float*)lds + it * 1024 + wid * 256;
                __builtin_amdgcn_global_load_lds(
                    (const __attribute__((address_space(1))) void*)src,
                    (__attribute__((address_space(3))) void*)dst, 16, 0, 0);
            }
            // advance D by 1024 dwords: 1024 = 6*168 + 16
            row += 6; rd += 16;
            if (rd >= LSTR) { rd -= LSTR; ++row; }
        }
    }
    __syncthreads();   // vmcnt drained at barrier

    // ---- Phase 1: all 4 samples' coordinates (pure VALU, no memory).
    SampCoord sc[4];
    sc[0] = scoord((float)y - a.x, (float)x       - a.y, AX0, AY0);
    sc[1] = scoord((float)y - a.z, (float)(x + 1) - a.w, AX0, AY0);
    sc[2] = scoord((float)y - c.x, (float)x       - c.y, AX0, AY0);
    sc[3] = scoord((float)y - c.z, (float)(x + 1) - c.w, AX0, AY0);

    // ---- Phase 2: batch the LDS reads. Wave-uniform fast path: all 256
    // lanes' samples in-apron (common) -> 24 ds_read2_b32 issued in one
    // block, single lgkmcnt region, zero divergence.
    float vals[4][12];
    const bool allok = sc[0].ok & sc[1].ok & sc[2].ok & sc[3].ok;
    if (__builtin_expect((bool)__all(allok), 1)) {
#pragma unroll
        for (int s = 0; s < 4; ++s) load12_lds(lds, sc[s], vals[s]);
    } else {
#pragma unroll
        for (int s = 0; s < 4; ++s) {
            if (sc[s].ok) load12_lds(lds, sc[s], vals[s]);
            else          load12_glb(imgb, sc[s], AX0, AY0, vals[s]);
        }
    }

    // ---- Phase 3: math + stores.
    float resA[6], resB[6];
    lerp3(sc[0], vals[0], resA);
    lerp3(sc[1], vals[1], resA + 3);
    lerp3(sc[2], vals[2], resB);
    lerp3(sc[3], vals[3], resB + 3);

    float* oA = out + (opA * NPIX + pixIn) * 3;
    float* oB = out + (opB * NPIX + pixIn) * 3;
    fv2 a0s = {resA[0], resA[1]};
    fv2 a1s = {resA[2], resA[3]};
    fv2 a2s = {resA[4], resA[5]};
    fv2 b0s = {resB[0], resB[1]};
    fv2 b1s = {resB[2], resB[3]};
    fv2 b2s = {resB[4], resB[5]};
    __builtin_nontemporal_store(a0s, (fv2*)oA);
    __builtin_nontemporal_store(a1s, (fv2*)oA + 1);
    __builtin_nontemporal_store(a2s, (fv2*)oA + 2);
    __builtin_nontemporal_store(b0s, (fv2*)oB);
    __builtin_nontemporal_store(b1s, (fv2*)oB + 1);
    __builtin_nontemporal_store(b2s, (fv2*)oB + 2);
}

extern "C" void kernel_launch(void* const* d_in, const int* in_sizes, int n_in,
                              void* d_out, int out_size, void* d_ws, size_t ws_size,
                              hipStream_t stream) {
    const float* frame0 = (const float*)d_in[0];
    const float* frame1 = (const float*)d_in[1];
    const float* f01    = (const float*)d_in[2];
    const float* f10    = (const float*)d_in[3];
    const float* ft0    = (const float*)d_in[4];
    const float* ft1    = (const float*)d_in[5];
    float* out = (float*)d_out;

    // 2 frame-groups * 16 b * 512 tiles = 16384 blocks of 256 threads.
    hipLaunchKernelGGL(warp_batch_kernel, dim3(16384), dim3(256), 0, stream,
                       frame0, frame1, f01, f10, ft0, ft1, out);
}

// Round 14
// 92.066 us; speedup vs baseline: 1.0632x; 1.0632x over previous
//
#include <hip/hip_runtime.h>

// (B,H,W,C) = (16,512,512,3) float32. 4 warp ops.
// out concat order: 0:(frame1,f01) 1:(frame0,f10) 2:(frame0,ft0) 3:(frame1,ft1)
#define HH 512
#define WW 512
#define NPIX (16 * HH * WW)
#define IMG_DW (HH * WW * 3)     // dwords per image
#define ROWD_G (WW * 3)          // global image row stride in dwords

#define TSX   32                 // output tile width
#define TSY   32                 // output tile height (32x32: apron ratio 3.06x)
#define APRX  12                 // x apron
#define APRY  12                 // y apron
#define LWX   (TSX + 2 * APRX)   // 56: staged region width (px)
#define LWY   (TSY + 2 * APRY)   // 56: staged region height (rows)
#define LSTR  (LWX * 3)          // 168: row stride (16B chunk-aligned: 168%4==0)
#define LDSDW (LWY * LSTR)       // 9408 dwords = 37,632 B -> 4 blocks/CU of 512thr
                                 //   = 32 waves/CU (100% occupancy ceiling)
#define NCHUNK (LDSDW / 4)       // 2352 16B chunks = 4*512 + 304
#define NTHR  512

typedef float fv4 __attribute__((ext_vector_type(4)));
typedef float fv2 __attribute__((ext_vector_type(2)));
typedef fv4 fv4u __attribute__((aligned(4)));
typedef fv2 fv2u __attribute__((aligned(4)));

__device__ __forceinline__ void sample(const float* __restrict__ imgb,
                                       const float* __restrict__ s,
                                       int AX0, int AY0,
                                       float qy, float qx, float* __restrict__ r)
{
    float fy = floorf(qy); fy = fminf(fmaxf(fy, 0.0f), (float)(HH - 2));
    float fx = floorf(qx); fx = fminf(fmaxf(fx, 0.0f), (float)(WW - 2));
    const float ay = fminf(fmaxf(qy - fy, 0.0f), 1.0f);
    const float ax = fminf(fmaxf(qx - fx, 0.0f), 1.0f);
    const int y0 = (int)fy, x0 = (int)fx;
    const int yl = y0 - AY0, xl = x0 - AX0;
    if ((unsigned)yl < (unsigned)(LWY - 1) && (unsigned)xl < (unsigned)(LWX - 1)) {
        // LDS path: AoS rows; 6x ds_read2_b32 (dword imm offsets <= 171 < 256)
        const float* t  = s + yl * LSTR + 3 * xl;
        const float* bo = t + LSTR;
#pragma unroll
        for (int c = 0; c < 3; ++c) {
            const float tl = t[c],  tr = t[c + 3];
            const float bl = bo[c], br = bo[c + 3];
            const float top = tl + ax * (tr - tl);
            const float bot = bl + ax * (br - bl);
            r[c] = top + ay * (bot - top);
        }
    } else {
        // rare global fallback (|flow| beyond apron): exact same math
        const float* t  = imgb + ((size_t)y0 * WW + x0) * 3;
        const float* bo = t + WW * 3;
        const fv4u t4 = *(const fv4u*)t;  const fv2u t2 = *(const fv2u*)(t + 4);
        const fv4u b4 = *(const fv4u*)bo; const fv2u b2 = *(const fv2u*)(bo + 4);
        const float tv[6] = {t4.x, t4.y, t4.z, t4.w, t2.x, t2.y};
        const float bv[6] = {b4.x, b4.y, b4.z, b4.w, b2.x, b2.y};
#pragma unroll
        for (int c = 0; c < 3; ++c) {
            const float top = tv[c] + ax * (tv[c + 3] - tv[c]);
            const float bot = bv[c] + ax * (bv[c + 3] - bv[c]);
            r[c] = top + ay * (bot - top);
        }
    }
}

__global__ __launch_bounds__(NTHR) void warp_t32_kernel(
    const float* __restrict__ frame0, const float* __restrict__ frame1,
    const float* __restrict__ f01, const float* __restrict__ f10,
    const float* __restrict__ ft0, const float* __restrict__ ft1,
    float* __restrict__ out)
{
    __shared__ float lds[LDSDW];   // 37,632 B -> 4 blocks/CU (32 waves, 100%)

    // 8192 blocks; bijective XCD chunking: XCD k gets 1024 contiguous units
    // = 4 whole (fg,b) images (3 MB fits 4 MB per-XCD L2); consecutive units
    // walk one image row-by-row so apron overlap stays L2-hot.
    const unsigned bid = blockIdx.x;
    const unsigned v   = (bid & 7u) * 1024u + (bid >> 3);

    const unsigned tile  = v & 255u;   // 16 x 16 tiles per image
    const unsigned img_b = v >> 8;     // 0..31
    const int b  = (int)(img_b & 15u);
    const int fg = (int)(img_b >> 4);  // 0: frame0 ops{1,2}, 1: frame1 ops{0,3}

    const int tx = (int)(tile & 15u);
    const int ty = (int)(tile >> 4);
    const int X0 = tx * TSX, Y0 = ty * TSY;
    const int AX0 = X0 - APRX, AY0 = Y0 - APRY;

    const float* img   = fg ? frame1 : frame0;
    const float* flowA = fg ? f01 : f10;
    const float* flowB = fg ? ft1 : ft0;
    const size_t opA   = fg ? 0 : 1;
    const size_t opB   = fg ? 3 : 2;

    const float* imgb = img + (size_t)b * IMG_DW;

    const int tid = (int)threadIdx.x;
    const int lx = (tid & 15) * 2;     // 16 threads x 2 px cover 32 px row
    const int ly = tid >> 4;           // 32 rows
    const int x = X0 + lx, y = Y0 + ly;
    const size_t pixIn = ((size_t)b * HH + y) * WW + x;

    // Flow loads FIRST (oldest in vmcnt queue): the scoord math below waits
    // only for these, not for the glds batch issued after.
    const fv4 a = __builtin_nontemporal_load((const fv4*)(flowA + pixIn * 2));
    const fv4 c = __builtin_nontemporal_load((const fv4*)(flowB + pixIn * 2));

    // ---- Stage apron region HBM -> LDS via global_load_lds (async, 0 VGPR).
    // 2352 16B chunks; thread tid handles chunk it*512+tid. LDS dest is
    // wave-uniform base + lane*16 (HW contract); LSTR%4==0, rows unpadded so
    // every chunk is pure payload within one region row. Out-of-image apron
    // cells are never read (bilinear clip); source clamp is fault-safety only.
    {
        const unsigned wid = __builtin_amdgcn_readfirstlane((unsigned)tid >> 6);
        int D   = tid * 4;             // LDS dword index of this thread's chunk
        int row = D / LSTR;            // magic-mul, once
        int rd  = D - row * LSTR;
#pragma unroll
        for (int it = 0; it < 5; ++it) {
            if (it < 4 || tid < (NCHUNK - 4 * NTHR)) {  // 304 tail chunks
                const int gy = min(max(AY0 + row, 0), HH - 1);
                int idx = gy * ROWD_G + AX0 * 3 + rd;
                idx = min(max(idx, 0), IMG_DW - 4);
                const float* src = imgb + idx;
                float* dst = (float*)lds + it * (NTHR * 4) + wid * 256;
                __builtin_amdgcn_global_load_lds(
                    (const __attribute__((address_space(1))) void*)src,
                    (__attribute__((address_space(3))) void*)dst, 16, 0, 0);
            }
            // advance D by 2048 dwords: 2048 = 12*168 + 32
            row += 12; rd += 32;
            if (rd >= LSTR) { rd -= LSTR; ++row; }
        }
    }

    // ---- Overlap: per-sample coordinate math runs while glds drain.
    // (waits vmcnt only down to the flow loads, which precede the glds batch)
    float qy0 = (float)y - a.x, qx0 = (float)x       - a.y;
    float qy1 = (float)y - a.z, qx1 = (float)(x + 1) - a.w;
    float qy2 = (float)y - c.x, qx2 = (float)x       - c.y;
    float qy3 = (float)y - c.z, qx3 = (float)(x + 1) - c.w;

    __syncthreads();   // drains the glds batch

    float* oA = out + (opA * NPIX + pixIn) * 3;
    float* oB = out + (opB * NPIX + pixIn) * 3;

    // Op A: 2 samples, store immediately (short live-range).
    {
        float res[6];
        sample(imgb, lds, AX0, AY0, qy0, qx0, res);
        sample(imgb, lds, AX0, AY0, qy1, qx1, res + 3);
        fv2 v0s = {res[0], res[1]};
        fv2 v1s = {res[2], res[3]};
        fv2 v2s = {res[4], res[5]};
        __builtin_nontemporal_store(v0s, (fv2*)oA);
        __builtin_nontemporal_store(v1s, (fv2*)oA + 1);
        __builtin_nontemporal_store(v2s, (fv2*)oA + 2);
    }
    // Op B
    {
        float res[6];
        sample(imgb, lds, AX0, AY0, qy2, qx2, res);
        sample(imgb, lds, AX0, AY0, qy3, qx3, res + 3);
        fv2 v0s = {res[0], res[1]};
        fv2 v1s = {res[2], res[3]};
        fv2 v2s = {res[4], res[5]};
        __builtin_nontemporal_store(v0s, (fv2*)oB);
        __builtin_nontemporal_store(v1s, (fv2*)oB + 1);
        __builtin_nontemporal_store(v2s, (fv2*)oB + 2);
    }
}

extern "C" void kernel_launch(void* const* d_in, const int* in_sizes, int n_in,
                              void* d_out, int out_size, void* d_ws, size_t ws_size,
                              hipStream_t stream) {
    const float* frame0 = (const float*)d_in[0];
    const float* frame1 = (const float*)d_in[1];
    const float* f01    = (const float*)d_in[2];
    const float* f10    = (const float*)d_in[3];
    const float* ft0    = (const float*)d_in[4];
    const float* ft1    = (const float*)d_in[5];
    float* out = (float*)d_out;

    // 2 frame-groups * 16 b * 256 tiles = 8192 blocks of 512 threads.
    hipLaunchKernelGGL(warp_t32_kernel, dim3(8192), dim3(NTHR), 0, stream,
                       frame0, frame1, f01, f10, ft0, ft1, out);
}